// Round 6
// baseline (505.049 us; speedup 1.0000x reference)
//
#include <hip/hip_runtime.h>
#include <cstdint>
#include <cstddef>

// ---------- types ----------
typedef __bf16 bf16_t;
typedef __bf16 bf16x8 __attribute__((ext_vector_type(8)));
typedef __bf16 bf16x4 __attribute__((ext_vector_type(4)));
typedef short s16x4 __attribute__((ext_vector_type(4)));
typedef float f32x4 __attribute__((ext_vector_type(4)));

// async global->LDS, 16B per lane. LDS dest must be wave-uniform base + lane*16.
#define GL2LDS16(gptr, lptr)                                                   \
  __builtin_amdgcn_global_load_lds(                                            \
      (__attribute__((address_space(1))) void*)(gptr),                         \
      (__attribute__((address_space(3))) void*)(lptr), 16, 0, 0)

// fast 2^x (hardware transcendental; inputs bounded here)
__device__ __forceinline__ float fast_exp2(float x) {
  float r;
  asm volatile("v_exp_f32 %0, %1" : "=v"(r) : "v"(x));
  return r;
}

// mfma 16x16x16 bf16 (K=16): A/B 4 bf16/lane (k = (lane>>4)*4 + j)
__device__ __forceinline__ f32x4 mfma16(bf16x4 a, bf16x4 b, f32x4 c) {
#if __has_builtin(__builtin_amdgcn_mfma_f32_16x16x16bf16_1k)
  return __builtin_amdgcn_mfma_f32_16x16x16bf16_1k(
      __builtin_bit_cast(s16x4, a), __builtin_bit_cast(s16x4, b), c, 0, 0, 0);
#else
  f32x4 d = c;
  asm volatile("v_mfma_f32_16x16x16_bf16 %0, %1, %2, %0"
               : "+v"(d) : "v"(a), "v"(b));
  return d;
#endif
}

// ---------- problem constants ----------
#define BATCH 2
#define T_SEQ 2048
#define NH 16
#define NKV 4
#define HD 128
#define EMB 2048
#define KVDIM (NKV * HD)       // 512
#define MROWS (BATCH * T_SEQ)  // 4096

// =====================================================================
// fused fp32 -> bf16 conversion for all 5 inputs (one dispatch)
// =====================================================================
__global__ void cvt_all(const float4* __restrict__ x,  const float4* __restrict__ wq,
                        const float4* __restrict__ wk, const float4* __restrict__ wv,
                        const float4* __restrict__ wo,
                        bf16x4* __restrict__ xb,  bf16x4* __restrict__ wqb,
                        bf16x4* __restrict__ wkb, bf16x4* __restrict__ wvb,
                        bf16x4* __restrict__ wob) {
  const int blk = blockIdx.x;
  const float4* src;
  bf16x4* dst;
  int base;
  if (blk < 8192)       { src = x;  dst = xb;  base = blk; }
  else if (blk < 12288) { src = wq; dst = wqb; base = blk - 8192; }
  else if (blk < 13312) { src = wk; dst = wkb; base = blk - 12288; }
  else if (blk < 14336) { src = wv; dst = wvb; base = blk - 13312; }
  else                  { src = wo; dst = wob; base = blk - 14336; }
  const int i = base * 256 + threadIdx.x;
  const float4 v = src[i];
  dst[i] = bf16x4{(__bf16)v.x, (__bf16)v.y, (__bf16)v.z, (__bf16)v.w};
}

// =====================================================================
// Fused QKV GEMM (m97 structure). N-blocks: [0,16) Q | [16,20) K | [20,24) V^T
// =====================================================================
__global__ __launch_bounds__(256, 2)
void gemm_qkv(const bf16_t* __restrict__ A,
              const bf16_t* __restrict__ Wq, const bf16_t* __restrict__ Wk,
              const bf16_t* __restrict__ Wv,
              bf16_t* __restrict__ Qb, bf16_t* __restrict__ Kb,
              bf16_t* __restrict__ Vt, float qalpha)
{
  __shared__ bf16_t As[128 * 64];
  __shared__ bf16_t Bs[128 * 64];

  const int tid  = threadIdx.x;
  const int lane = tid & 63;
  const int wv   = tid >> 6;
  const int nbx = blockIdx.x;
  const int m0 = blockIdx.y * 128;
  const int wm = (wv >> 1) * 64;
  const int wn = (wv & 1) * 64;
  const int l15 = lane & 15;
  const int lq  = lane >> 4;

  const bf16_t* Bm;
  int ncol0;
  if (nbx < 16)      { Bm = Wq; ncol0 = nbx * 128; }
  else if (nbx < 20) { Bm = Wk; ncol0 = (nbx - 16) * 128; }
  else               { Bm = Wv; ncol0 = (nbx - 20) * 128; }

  f32x4 acc[4][4] = {};
  const int srow = tid >> 3;
  const int scol = (tid & 7) * 8;

  for (int k0 = 0; k0 < EMB; k0 += 64) {
#pragma unroll
    for (int r = 0; r < 4; ++r) {
      const int row = r * 32 + srow;
      GL2LDS16(A + (size_t)(m0 + row) * EMB + k0 + scol, As + row * 64 + scol);
    }
#pragma unroll
    for (int r = 0; r < 4; ++r) {
      const int row = r * 32 + srow;
      GL2LDS16(Bm + (size_t)(ncol0 + row) * EMB + k0 + scol, Bs + row * 64 + scol);
    }
    __syncthreads();

#pragma unroll
    for (int ks = 0; ks < 2; ++ks) {
      const int kc = ks * 32 + lq * 8;
      bf16x8 af[4], bf[4];
#pragma unroll
      for (int i = 0; i < 4; ++i)
        af[i] = *(const bf16x8*)(As + (wm + i * 16 + l15) * 64 + kc);
#pragma unroll
      for (int j = 0; j < 4; ++j)
        bf[j] = *(const bf16x8*)(Bs + (wn + j * 16 + l15) * 64 + kc);
#pragma unroll
      for (int i = 0; i < 4; ++i)
#pragma unroll
        for (int j = 0; j < 4; ++j)
          acc[i][j] = __builtin_amdgcn_mfma_f32_16x16x32_bf16(af[i], bf[j], acc[i][j], 0, 0, 0);
    }
    __syncthreads();
  }

  if (nbx < 16) {          // Q: scale + row-major
#pragma unroll
    for (int i = 0; i < 4; ++i) {
      const int rbase = m0 + wm + i * 16 + lq * 4;
#pragma unroll
      for (int j = 0; j < 4; ++j) {
        const int col = ncol0 + wn + j * 16 + l15;
#pragma unroll
        for (int r = 0; r < 4; ++r)
          Qb[(size_t)(rbase + r) * EMB + col] = (bf16_t)(acc[i][j][r] * qalpha);
      }
    }
  } else if (nbx < 20) {   // K: row-major (4096,512)
#pragma unroll
    for (int i = 0; i < 4; ++i) {
      const int rbase = m0 + wm + i * 16 + lq * 4;
#pragma unroll
      for (int j = 0; j < 4; ++j) {
        const int col = ncol0 + wn + j * 16 + l15;
#pragma unroll
        for (int r = 0; r < 4; ++r)
          Kb[(size_t)(rbase + r) * KVDIM + col] = (bf16_t)acc[i][j][r];
      }
    }
  } else {                 // V: transposed, 4 consecutive t per lane
    const int b = m0 >> 11;
    const int mloc0 = (m0 & 2047) + wm + lq * 4;
#pragma unroll
    for (int i = 0; i < 4; ++i) {
      const int mloc = mloc0 + i * 16;
#pragma unroll
      for (int j = 0; j < 4; ++j) {
        const int d = ncol0 + wn + j * 16 + l15;
        *(bf16x4*)(Vt + (size_t)(b * KVDIM + d) * T_SEQ + mloc) =
            bf16x4{(__bf16)acc[i][j][0], (__bf16)acc[i][j][1],
                   (__bf16)acc[i][j][2], (__bf16)acc[i][j][3]};
      }
    }
  }
}

// =====================================================================
// GEMM (out-projection): fp32 out.
// =====================================================================
__global__ __launch_bounds__(256, 2)
void gemm_out(const bf16_t* __restrict__ A, const bf16_t* __restrict__ Bm,
              float* __restrict__ C, int M, int N, int K)
{
  __shared__ bf16_t As[128 * 64];
  __shared__ bf16_t Bs[128 * 64];

  const int tid  = threadIdx.x;
  const int lane = tid & 63;
  const int wv   = tid >> 6;
  const int m0 = blockIdx.y * 128;
  const int n0 = blockIdx.x * 128;
  const int wm = (wv >> 1) * 64;
  const int wn = (wv & 1) * 64;
  const int l15 = lane & 15;
  const int lq  = lane >> 4;

  f32x4 acc[4][4] = {};
  const int srow = tid >> 3;
  const int scol = (tid & 7) * 8;

  for (int k0 = 0; k0 < K; k0 += 64) {
#pragma unroll
    for (int r = 0; r < 4; ++r) {
      const int row = r * 32 + srow;
      GL2LDS16(A + (size_t)(m0 + row) * K + k0 + scol, As + row * 64 + scol);
    }
#pragma unroll
    for (int r = 0; r < 4; ++r) {
      const int row = r * 32 + srow;
      GL2LDS16(Bm + (size_t)(n0 + row) * K + k0 + scol, Bs + row * 64 + scol);
    }
    __syncthreads();

#pragma unroll
    for (int ks = 0; ks < 2; ++ks) {
      const int kc = ks * 32 + lq * 8;
      bf16x8 af[4], bf[4];
#pragma unroll
      for (int i = 0; i < 4; ++i)
        af[i] = *(const bf16x8*)(As + (wm + i * 16 + l15) * 64 + kc);
#pragma unroll
      for (int j = 0; j < 4; ++j)
        bf[j] = *(const bf16x8*)(Bs + (wn + j * 16 + l15) * 64 + kc);
#pragma unroll
      for (int i = 0; i < 4; ++i)
#pragma unroll
        for (int j = 0; j < 4; ++j)
          acc[i][j] = __builtin_amdgcn_mfma_f32_16x16x32_bf16(af[i], bf[j], acc[i][j], 0, 0, 0);
    }
    __syncthreads();
  }

#pragma unroll
  for (int i = 0; i < 4; ++i) {
    const int rbase = m0 + wm + i * 16 + lq * 4;
#pragma unroll
    for (int j = 0; j < 4; ++j) {
      const int col = n0 + wn + j * 16 + l15;
#pragma unroll
      for (int r = 0; r < 4; ++r)
        C[(size_t)(rbase + r) * N + col] = acc[i][j][r];
    }
  }
}

// =====================================================================
// Flash attention, causal, GQA, no-max exp2 softmax.
// q-tile 128/block (4 waves x 2 q-groups of 16); kv tile 64.
// S^T via 16x16x32 (shared K frags); PV via 16x16x16 DIRECT from s regs
// (S^T C-layout == PV B-operand layout) -> no P LDS, ONE barrier/iter.
// K & V double-buffered via global_load_lds; LDS = 64 KiB exactly (2/CU).
// Grid (16,NH,B) = 512 blocks = 2/CU; qt = 15-x (heavy first, FIFO balance).
// =====================================================================
__global__ __launch_bounds__(256, 2)
void attn_fwd(const bf16_t* __restrict__ Q, const bf16_t* __restrict__ Kg,
              const bf16_t* __restrict__ Vt, bf16_t* __restrict__ Y)
{
  __shared__ bf16_t Ks[2][64 * 128];   // [t][16B blk], blk = pos ^ (t&7)
  __shared__ bf16_t Vs[2][128 * 64];   // [d][16B blk], blk = pos ^ (d&7)

  const int tid  = threadIdx.x;
  const int lane = tid & 63;
  const int wv   = tid >> 6;
  const int l15  = lane & 15;
  const int lq   = lane >> 4;
  const int q7   = l15 & 7;
  const int h  = blockIdx.y;
  const int b  = blockIdx.z;
  const int hkv = h >> 2;

  const int qt = 15 - blockIdx.x;
  const int q0 = qt * 128;
  const int nkt = 2 * qt + 2;
  const int qa0 = q0 + wv * 16 + l15;       // group-0 q row
  const int qa1 = qa0 + 64;                 // group-1 q row

  auto stageK = [&](int kt, int bufsel) {
    const int base_t = b * T_SEQ + kt * 64;
#pragma unroll
    for (int r = 0; r < 4; ++r) {
      const int c = r * 256 + tid;
      const int row = c >> 4, p = c & 15;
      const int sb = p ^ (row & 7);
      GL2LDS16(Kg + (size_t)(base_t + row) * KVDIM + hkv * HD + sb * 8,
               &Ks[bufsel][c * 8]);
    }
  };
  auto stageV = [&](int kt, int bufsel) {
#pragma unroll
    for (int r = 0; r < 4; ++r) {
      const int c = r * 256 + tid;
      const int row = c >> 3, p = c & 7;
      const int sb = p ^ (row & 7);
      GL2LDS16(Vt + (size_t)(b * KVDIM + hkv * HD + row) * T_SEQ + kt * 64 + sb * 8,
               &Vs[bufsel][c * 8]);
    }
  };

  // Q fragments (B-operand of x32: n=l15=q, k=lq*8+j). Q pre-scaled.
  bf16x8 qf0[4], qf1[4];
  {
    const bf16_t* qp0 = Q + ((size_t)(b * T_SEQ + qa0) * NH + h) * HD + lq * 8;
    const bf16_t* qp1 = Q + ((size_t)(b * T_SEQ + qa1) * NH + h) * HD + lq * 8;
#pragma unroll
    for (int ds = 0; ds < 4; ++ds) {
      qf0[ds] = *(const bf16x8*)(qp0 + ds * 32);
      qf1[ds] = *(const bf16x8*)(qp1 + ds * 32);
    }
  }

  float l0 = 0.f, l1 = 0.f;
  f32x4 o0[8], o1[8];
#pragma unroll
  for (int nb = 0; nb < 8; ++nb) {
    o0[nb] = f32x4{0.f, 0.f, 0.f, 0.f};
    o1[nb] = f32x4{0.f, 0.f, 0.f, 0.f};
  }

  stageK(0, 0);
  stageV(0, 0);

  for (int kt = 0; kt < nkt; ++kt) {
    const int cur = kt & 1;
    __syncthreads();            // staging of tile kt complete
    if (kt + 1 < nkt) { stageK(kt + 1, cur ^ 1); stageV(kt + 1, cur ^ 1); }

    const bool g0 = (kt < nkt - 1);   // group-0 skips its fully-masked tile

    // ---- S^T = K Q^T (both groups; K frags read once) ----
    f32x4 s0[4], s1[4];
#pragma unroll
    for (int nb = 0; nb < 4; ++nb) {
      s0[nb] = f32x4{0.f, 0.f, 0.f, 0.f};
      s1[nb] = f32x4{0.f, 0.f, 0.f, 0.f};
      const int row = nb * 16 + l15;
      const int r7  = row & 7;
#pragma unroll
      for (int ds = 0; ds < 4; ++ds) {
        const bf16x8 kf = *(const bf16x8*)&Ks[cur][row * 128 + (((ds * 4 + lq) ^ r7) * 8)];
        if (g0) s0[nb] = __builtin_amdgcn_mfma_f32_16x16x32_bf16(kf, qf0[ds], s0[nb], 0, 0, 0);
        s1[nb] = __builtin_amdgcn_mfma_f32_16x16x32_bf16(kf, qf1[ds], s1[nb], 0, 0, 0);
      }
    }

    // ---- p = exp2(s) into REGISTER bf16x4 fragments (PV B-operands) ----
    bf16x4 pf0[4], pf1[4];
    if (g0) {
      const bool dia = (kt == nkt - 2);
#pragma unroll
      for (int nb = 0; nb < 4; ++nb) {
        const int kvb = kt * 64 + nb * 16 + lq * 4;
        float p0, p1, p2, p3;
        if (dia) {
          p0 = (kvb + 0 <= qa0) ? fast_exp2(s0[nb][0]) : 0.f;
          p1 = (kvb + 1 <= qa0) ? fast_exp2(s0[nb][1]) : 0.f;
          p2 = (kvb + 2 <= qa0) ? fast_exp2(s0[nb][2]) : 0.f;
          p3 = (kvb + 3 <= qa0) ? fast_exp2(s0[nb][3]) : 0.f;
        } else {
          p0 = fast_exp2(s0[nb][0]); p1 = fast_exp2(s0[nb][1]);
          p2 = fast_exp2(s0[nb][2]); p3 = fast_exp2(s0[nb][3]);
        }
        l0 += (p0 + p1) + (p2 + p3);
        pf0[nb] = bf16x4{(__bf16)p0, (__bf16)p1, (__bf16)p2, (__bf16)p3};
      }
    }
    {
      const bool dia = (kt == nkt - 1);
#pragma unroll
      for (int nb = 0; nb < 4; ++nb) {
        const int kvb = kt * 64 + nb * 16 + lq * 4;
        float p0, p1, p2, p3;
        if (dia) {
          p0 = (kvb + 0 <= qa1) ? fast_exp2(s1[nb][0]) : 0.f;
          p1 = (kvb + 1 <= qa1) ? fast_exp2(s1[nb][1]) : 0.f;
          p2 = (kvb + 2 <= qa1) ? fast_exp2(s1[nb][2]) : 0.f;
          p3 = (kvb + 3 <= qa1) ? fast_exp2(s1[nb][3]) : 0.f;
        } else {
          p0 = fast_exp2(s1[nb][0]); p1 = fast_exp2(s1[nb][1]);
          p2 = fast_exp2(s1[nb][2]); p3 = fast_exp2(s1[nb][3]);
        }
        l1 += (p0 + p1) + (p2 + p3);
        pf1[nb] = bf16x4{(__bf16)p0, (__bf16)p1, (__bf16)p2, (__bf16)p3};
      }
    }

    // ---- O^T += V^T P^T : K=16 MFMA, P straight from registers ----
#pragma unroll
    for (int dt = 0; dt < 8; ++dt) {
      const int row = dt * 16 + l15;
#pragma unroll
      for (int nb = 0; nb < 4; ++nb) {
        const bf16x4 vf = *(const bf16x4*)&Vs[cur][row * 64 +
            ((((nb << 1) | (lq >> 1)) ^ q7) << 3) + ((lq & 1) << 2)];
        if (g0) o0[dt] = mfma16(vf, pf0[nb], o0[dt]);
        o1[dt] = mfma16(vf, pf1[nb], o1[dt]);
      }
    }
  }

  // ---- epilogue: reduce l over lq group, store Y (B,T,NH,HD) ----
  {
    float lt = l0;
    lt += __shfl_xor(lt, 16);
    lt += __shfl_xor(lt, 32);
    const float inv = 1.f / lt;
    bf16_t* yp = Y + ((size_t)(b * T_SEQ + qa0) * NH + h) * HD + lq * 4;
#pragma unroll
    for (int nb = 0; nb < 8; ++nb)
      *(bf16x4*)(yp + nb * 16) = bf16x4{(__bf16)(o0[nb][0] * inv), (__bf16)(o0[nb][1] * inv),
                                        (__bf16)(o0[nb][2] * inv), (__bf16)(o0[nb][3] * inv)};
  }
  {
    float lt = l1;
    lt += __shfl_xor(lt, 16);
    lt += __shfl_xor(lt, 32);
    const float inv = 1.f / lt;
    bf16_t* yp = Y + ((size_t)(b * T_SEQ + qa1) * NH + h) * HD + lq * 4;
#pragma unroll
    for (int nb = 0; nb < 8; ++nb)
      *(bf16x4*)(yp + nb * 16) = bf16x4{(__bf16)(o1[nb][0] * inv), (__bf16)(o1[nb][1] * inv),
                                        (__bf16)(o1[nb][2] * inv), (__bf16)(o1[nb][3] * inv)};
  }
}

// =====================================================================
// launch
// =====================================================================
extern "C" void kernel_launch(void* const* d_in, const int* in_sizes, int n_in,
                              void* d_out, int out_size, void* d_ws, size_t ws_size,
                              hipStream_t stream) {
  const float* x  = (const float*)d_in[0];
  const float* wq = (const float*)d_in[1];
  const float* wk = (const float*)d_in[2];
  const float* wv = (const float*)d_in[3];
  const float* wo = (const float*)d_in[4];
  float* out = (float*)d_out;

  const size_t n_x  = (size_t)MROWS * EMB;
  const size_t n_wq = (size_t)EMB * EMB;
  const size_t n_wk = (size_t)KVDIM * EMB;

  bf16_t* xb  = (bf16_t*)d_ws;
  bf16_t* wqb = xb  + n_x;
  bf16_t* wkb = wqb + n_wq;
  bf16_t* wvb = wkb + n_wk;
  bf16_t* wob = wvb + n_wk;
  bf16_t* Qb  = wob + n_wq;                  // 4096*2048
  bf16_t* Kb  = Qb + (size_t)MROWS * EMB;    // 4096*512
  bf16_t* Vtb = Kb + (size_t)MROWS * KVDIM;  // (B*512)*2048 transposed V
  bf16_t* Yb  = Vtb + (size_t)MROWS * KVDIM; // 4096*2048

  dim3 blk(256);

  cvt_all<<<dim3(18432), blk, 0, stream>>>(
      (const float4*)x, (const float4*)wq, (const float4*)wk, (const float4*)wv, (const float4*)wo,
      (bf16x4*)xb, (bf16x4*)wqb, (bf16x4*)wkb, (bf16x4*)wvb, (bf16x4*)wob);

  const float qalpha = 0.08838834764831845f * 1.4426950408889634f;
  gemm_qkv<<<dim3(24, MROWS / 128), blk, 0, stream>>>(xb, wqb, wkb, wvb,
                                                      Qb, Kb, Vtb, qalpha);

  attn_fwd<<<dim3(16, NH, BATCH), blk, 0, stream>>>(Qb, Kb, Vtb, Yb);

  gemm_out<<<dim3(EMB / 128, MROWS / 128), blk, 0, stream>>>(Yb, wob, out, MROWS, EMB, EMB);
}

// Round 7
// 282.348 us; speedup vs baseline: 1.7887x; 1.7887x over previous
//
#include <hip/hip_runtime.h>
#include <cstdint>
#include <cstddef>

// ---------- types ----------
typedef __bf16 bf16_t;
typedef __bf16 bf16x8 __attribute__((ext_vector_type(8)));
typedef __bf16 bf16x4 __attribute__((ext_vector_type(4)));
typedef float f32x4 __attribute__((ext_vector_type(4)));

// async global->LDS, 16B per lane. LDS dest must be wave-uniform base + lane*16.
#define GL2LDS16(gptr, lptr)                                                   \
  __builtin_amdgcn_global_load_lds(                                            \
      (__attribute__((address_space(1))) void*)(gptr),                         \
      (__attribute__((address_space(3))) void*)(lptr), 16, 0, 0)

// fast 2^x (hardware transcendental; inputs bounded here)
__device__ __forceinline__ float fast_exp2(float x) {
  float r;
  asm volatile("v_exp_f32 %0, %1" : "=v"(r) : "v"(x));
  return r;
}

// ---------- problem constants ----------
#define BATCH 2
#define T_SEQ 2048
#define NH 16
#define NKV 4
#define HD 128
#define EMB 2048
#define KVDIM (NKV * HD)       // 512
#define MROWS (BATCH * T_SEQ)  // 4096

// =====================================================================
// fused fp32 -> bf16 conversion for all 5 inputs (one dispatch)
// =====================================================================
__global__ void cvt_all(const float4* __restrict__ x,  const float4* __restrict__ wq,
                        const float4* __restrict__ wk, const float4* __restrict__ wv,
                        const float4* __restrict__ wo,
                        bf16x4* __restrict__ xb,  bf16x4* __restrict__ wqb,
                        bf16x4* __restrict__ wkb, bf16x4* __restrict__ wvb,
                        bf16x4* __restrict__ wob) {
  const int blk = blockIdx.x;
  const float4* src;
  bf16x4* dst;
  int base;
  if (blk < 8192)       { src = x;  dst = xb;  base = blk; }
  else if (blk < 12288) { src = wq; dst = wqb; base = blk - 8192; }
  else if (blk < 13312) { src = wk; dst = wkb; base = blk - 12288; }
  else if (blk < 14336) { src = wv; dst = wvb; base = blk - 13312; }
  else                  { src = wo; dst = wob; base = blk - 14336; }
  const int i = base * 256 + threadIdx.x;
  const float4 v = src[i];
  dst[i] = bf16x4{(__bf16)v.x, (__bf16)v.y, (__bf16)v.z, (__bf16)v.w};
}

// =====================================================================
// Fused QKV GEMM (m97 structure). N-blocks: [0,16) Q | [16,20) K | [20,24) V^T
// =====================================================================
__global__ __launch_bounds__(256, 2)
void gemm_qkv(const bf16_t* __restrict__ A,
              const bf16_t* __restrict__ Wq, const bf16_t* __restrict__ Wk,
              const bf16_t* __restrict__ Wv,
              bf16_t* __restrict__ Qb, bf16_t* __restrict__ Kb,
              bf16_t* __restrict__ Vt, float qalpha)
{
  __shared__ bf16_t As[128 * 64];
  __shared__ bf16_t Bs[128 * 64];

  const int tid  = threadIdx.x;
  const int lane = tid & 63;
  const int wv   = tid >> 6;
  const int nbx = blockIdx.x;
  const int m0 = blockIdx.y * 128;
  const int wm = (wv >> 1) * 64;
  const int wn = (wv & 1) * 64;
  const int l15 = lane & 15;
  const int lq  = lane >> 4;

  const bf16_t* Bm;
  int ncol0;
  if (nbx < 16)      { Bm = Wq; ncol0 = nbx * 128; }
  else if (nbx < 20) { Bm = Wk; ncol0 = (nbx - 16) * 128; }
  else               { Bm = Wv; ncol0 = (nbx - 20) * 128; }

  f32x4 acc[4][4] = {};
  const int srow = tid >> 3;
  const int scol = (tid & 7) * 8;

  for (int k0 = 0; k0 < EMB; k0 += 64) {
#pragma unroll
    for (int r = 0; r < 4; ++r) {
      const int row = r * 32 + srow;
      GL2LDS16(A + (size_t)(m0 + row) * EMB + k0 + scol, As + row * 64 + scol);
    }
#pragma unroll
    for (int r = 0; r < 4; ++r) {
      const int row = r * 32 + srow;
      GL2LDS16(Bm + (size_t)(ncol0 + row) * EMB + k0 + scol, Bs + row * 64 + scol);
    }
    __syncthreads();

#pragma unroll
    for (int ks = 0; ks < 2; ++ks) {
      const int kc = ks * 32 + lq * 8;
      bf16x8 af[4], bf[4];
#pragma unroll
      for (int i = 0; i < 4; ++i)
        af[i] = *(const bf16x8*)(As + (wm + i * 16 + l15) * 64 + kc);
#pragma unroll
      for (int j = 0; j < 4; ++j)
        bf[j] = *(const bf16x8*)(Bs + (wn + j * 16 + l15) * 64 + kc);
#pragma unroll
      for (int i = 0; i < 4; ++i)
#pragma unroll
        for (int j = 0; j < 4; ++j)
          acc[i][j] = __builtin_amdgcn_mfma_f32_16x16x32_bf16(af[i], bf[j], acc[i][j], 0, 0, 0);
    }
    __syncthreads();
  }

  if (nbx < 16) {          // Q: scale + row-major
#pragma unroll
    for (int i = 0; i < 4; ++i) {
      const int rbase = m0 + wm + i * 16 + lq * 4;
#pragma unroll
      for (int j = 0; j < 4; ++j) {
        const int col = ncol0 + wn + j * 16 + l15;
#pragma unroll
        for (int r = 0; r < 4; ++r)
          Qb[(size_t)(rbase + r) * EMB + col] = (bf16_t)(acc[i][j][r] * qalpha);
      }
    }
  } else if (nbx < 20) {   // K: row-major (4096,512)
#pragma unroll
    for (int i = 0; i < 4; ++i) {
      const int rbase = m0 + wm + i * 16 + lq * 4;
#pragma unroll
      for (int j = 0; j < 4; ++j) {
        const int col = ncol0 + wn + j * 16 + l15;
#pragma unroll
        for (int r = 0; r < 4; ++r)
          Kb[(size_t)(rbase + r) * KVDIM + col] = (bf16_t)acc[i][j][r];
      }
    }
  } else {                 // V: transposed, 4 consecutive t per lane
    const int b = m0 >> 11;
    const int mloc0 = (m0 & 2047) + wm + lq * 4;
#pragma unroll
    for (int i = 0; i < 4; ++i) {
      const int mloc = mloc0 + i * 16;
#pragma unroll
      for (int j = 0; j < 4; ++j) {
        const int d = ncol0 + wn + j * 16 + l15;
        *(bf16x4*)(Vt + (size_t)(b * KVDIM + d) * T_SEQ + mloc) =
            bf16x4{(__bf16)acc[i][j][0], (__bf16)acc[i][j][1],
                   (__bf16)acc[i][j][2], (__bf16)acc[i][j][3]};
      }
    }
  }
}

// =====================================================================
// GEMM (out-projection): fp32 out.
// =====================================================================
__global__ __launch_bounds__(256, 2)
void gemm_out(const bf16_t* __restrict__ A, const bf16_t* __restrict__ Bm,
              float* __restrict__ C, int M, int N, int K)
{
  __shared__ bf16_t As[128 * 64];
  __shared__ bf16_t Bs[128 * 64];

  const int tid  = threadIdx.x;
  const int lane = tid & 63;
  const int wv   = tid >> 6;
  const int m0 = blockIdx.y * 128;
  const int n0 = blockIdx.x * 128;
  const int wm = (wv >> 1) * 64;
  const int wn = (wv & 1) * 64;
  const int l15 = lane & 15;
  const int lq  = lane >> 4;

  f32x4 acc[4][4] = {};
  const int srow = tid >> 3;
  const int scol = (tid & 7) * 8;

  for (int k0 = 0; k0 < K; k0 += 64) {
#pragma unroll
    for (int r = 0; r < 4; ++r) {
      const int row = r * 32 + srow;
      GL2LDS16(A + (size_t)(m0 + row) * K + k0 + scol, As + row * 64 + scol);
    }
#pragma unroll
    for (int r = 0; r < 4; ++r) {
      const int row = r * 32 + srow;
      GL2LDS16(Bm + (size_t)(n0 + row) * K + k0 + scol, Bs + row * 64 + scol);
    }
    __syncthreads();

#pragma unroll
    for (int ks = 0; ks < 2; ++ks) {
      const int kc = ks * 32 + lq * 8;
      bf16x8 af[4], bf[4];
#pragma unroll
      for (int i = 0; i < 4; ++i)
        af[i] = *(const bf16x8*)(As + (wm + i * 16 + l15) * 64 + kc);
#pragma unroll
      for (int j = 0; j < 4; ++j)
        bf[j] = *(const bf16x8*)(Bs + (wn + j * 16 + l15) * 64 + kc);
#pragma unroll
      for (int i = 0; i < 4; ++i)
#pragma unroll
        for (int j = 0; j < 4; ++j)
          acc[i][j] = __builtin_amdgcn_mfma_f32_16x16x32_bf16(af[i], bf[j], acc[i][j], 0, 0, 0);
    }
    __syncthreads();
  }

#pragma unroll
  for (int i = 0; i < 4; ++i) {
    const int rbase = m0 + wm + i * 16 + lq * 4;
#pragma unroll
    for (int j = 0; j < 4; ++j) {
      const int col = n0 + wn + j * 16 + l15;
#pragma unroll
      for (int r = 0; r < 4; ++r)
        C[(size_t)(rbase + r) * N + col] = acc[i][j][r];
    }
  }
}

// =====================================================================
// Flash attention (R4-verified structure: 65.7 µs, MfmaUtil 21.5%).
// Causal, GQA, no-max exp2 softmax, S^T orientation, P via per-wave LDS,
// x32 PV. q-tile 64 (16 rows/wave); kv tile 64; K/V double-buffered.
// Grid (16,NH,B): block x does qt=31-x then qt=x (33 iters, balanced).
// =====================================================================
#define PSTR 72   // row stride (elements); 144 B = 16B-aligned

__global__ __launch_bounds__(256, 2)
void attn_fwd(const bf16_t* __restrict__ Q, const bf16_t* __restrict__ Kg,
              const bf16_t* __restrict__ Vt, bf16_t* __restrict__ Y)
{
  __shared__ bf16_t Ks[2][64 * 128];   // [t 0..63][16B blk], blk = pos ^ (t&7)
  __shared__ bf16_t Vs[2][128 * 64];   // [d 0..127][16B blk], blk = pos ^ (d&7)
  __shared__ bf16_t Ps[4][16 * PSTR];  // per-wave P[q 0..15][kv 0..63]

  const int tid  = threadIdx.x;
  const int lane = tid & 63;
  const int wv   = tid >> 6;
  const int l15  = lane & 15;
  const int lq   = lane >> 4;
  const int h  = blockIdx.y;
  const int b  = blockIdx.z;
  const int hkv = h >> 2;
  bf16_t* Psw = Ps[wv];

  auto stage = [&](int kt, int bufsel) {
    const int base_t = b * T_SEQ + kt * 64;
#pragma unroll
    for (int r = 0; r < 4; ++r) {
      const int c = r * 256 + tid;
      const int row = c >> 4, p = c & 15;
      const int sb = p ^ (row & 7);
      GL2LDS16(Kg + (size_t)(base_t + row) * KVDIM + hkv * HD + sb * 8,
               &Ks[bufsel][c * 8]);
    }
#pragma unroll
    for (int r = 0; r < 4; ++r) {
      const int c = r * 256 + tid;
      const int row = c >> 3, p = c & 7;
      const int sb = p ^ (row & 7);
      GL2LDS16(Vt + (size_t)(b * KVDIM + hkv * HD + row) * T_SEQ + kt * 64 + sb * 8,
               &Vs[bufsel][c * 8]);
    }
  };

#pragma unroll 1
  for (int ph = 0; ph < 2; ++ph) {
    const int qt = ph ? blockIdx.x : (31 - blockIdx.x);
    const int q0 = qt * 64;
    const int nkt = qt + 1;
    const int qabs = q0 + wv * 16 + l15;   // this lane's q row

    // Q fragments (B-operand: n=l15=q, k=lq*8+j). Q pre-scaled.
    bf16x8 qf[4];
    {
      const bf16_t* qp = Q + ((size_t)(b * T_SEQ + qabs) * NH + h) * HD + lq * 8;
#pragma unroll
      for (int ds = 0; ds < 4; ++ds)
        qf[ds] = *(const bf16x8*)(qp + ds * 32);
    }

    float l_part = 0.f;
    f32x4 o[8];
#pragma unroll
    for (int nb = 0; nb < 8; ++nb) o[nb] = f32x4{0.f, 0.f, 0.f, 0.f};

    __syncthreads();            // prior phase done reading buffers
    stage(0, 0);

    for (int kt = 0; kt < nkt; ++kt) {
      const int cur = kt & 1;
      __syncthreads();          // stage(kt) complete
      if (kt + 1 < nkt) stage(kt + 1, cur ^ 1);

      // ---- S^T = K Q^T : D[kv][q], lane: q=l15, kv=nb*16+lq*4+r ----
      f32x4 s[4];
#pragma unroll
      for (int nb = 0; nb < 4; ++nb) {
        s[nb] = f32x4{0.f, 0.f, 0.f, 0.f};
        const int row = nb * 16 + l15;
        const int r7  = row & 7;
#pragma unroll
        for (int ds = 0; ds < 4; ++ds) {
          const bf16x8 kf = *(const bf16x8*)&Ks[cur][row * 128 + (((ds * 4 + lq) ^ r7) * 8)];
          s[nb] = __builtin_amdgcn_mfma_f32_16x16x32_bf16(kf, qf[ds], s[nb], 0, 0, 0);
        }
      }

      // ---- p = exp2(s) raw (no max), mask only on diagonal tile ----
      const bool dia = (kt == nkt - 1);
#pragma unroll
      for (int nb = 0; nb < 4; ++nb) {
        const int kvb = kt * 64 + nb * 16 + lq * 4;
        float p0, p1, p2, p3;
        if (dia) {
          p0 = (kvb + 0 <= qabs) ? fast_exp2(s[nb][0]) : 0.f;
          p1 = (kvb + 1 <= qabs) ? fast_exp2(s[nb][1]) : 0.f;
          p2 = (kvb + 2 <= qabs) ? fast_exp2(s[nb][2]) : 0.f;
          p3 = (kvb + 3 <= qabs) ? fast_exp2(s[nb][3]) : 0.f;
        } else {
          p0 = fast_exp2(s[nb][0]);
          p1 = fast_exp2(s[nb][1]);
          p2 = fast_exp2(s[nb][2]);
          p3 = fast_exp2(s[nb][3]);
        }
        l_part += (p0 + p1) + (p2 + p3);
        *(bf16x4*)(Psw + l15 * PSTR + nb * 16 + lq * 4) =
            bf16x4{(__bf16)p0, (__bf16)p1, (__bf16)p2, (__bf16)p3};
      }

      // wait ONLY LDS (keep K/V prefetch in flight)
      asm volatile("s_waitcnt lgkmcnt(0)" ::: "memory");

      // ---- O^T += V^T P^T : D[d][q], lane: q=l15, d=nb*16+lq*4+r ----
#pragma unroll
      for (int ks = 0; ks < 2; ++ks) {
        const bf16x8 pf = *(const bf16x8*)(Psw + l15 * PSTR + ks * 32 + lq * 8);
#pragma unroll
        for (int nb = 0; nb < 8; ++nb) {
          const int row = nb * 16 + l15;
          const bf16x8 vf = *(const bf16x8*)&Vs[cur][row * 64 + (((ks * 4 + lq) ^ (row & 7)) * 8)];
          o[nb] = __builtin_amdgcn_mfma_f32_16x16x32_bf16(vf, pf, o[nb], 0, 0, 0);
        }
      }
    }

    // ---- epilogue: reduce l over lq-group (lanes l15+16*lq), store ----
    float lt = l_part;
    lt += __shfl_xor(lt, 16);
    lt += __shfl_xor(lt, 32);
    const float inv = 1.f / lt;
    bf16_t* yp = Y + ((size_t)(b * T_SEQ + qabs) * NH + h) * HD + lq * 4;
#pragma unroll
    for (int nb = 0; nb < 8; ++nb) {
      *(bf16x4*)(yp + nb * 16) = bf16x4{(__bf16)(o[nb][0] * inv), (__bf16)(o[nb][1] * inv),
                                        (__bf16)(o[nb][2] * inv), (__bf16)(o[nb][3] * inv)};
    }
  }
}

// =====================================================================
// launch
// =====================================================================
extern "C" void kernel_launch(void* const* d_in, const int* in_sizes, int n_in,
                              void* d_out, int out_size, void* d_ws, size_t ws_size,
                              hipStream_t stream) {
  const float* x  = (const float*)d_in[0];
  const float* wq = (const float*)d_in[1];
  const float* wk = (const float*)d_in[2];
  const float* wv = (const float*)d_in[3];
  const float* wo = (const float*)d_in[4];
  float* out = (float*)d_out;

  const size_t n_x  = (size_t)MROWS * EMB;
  const size_t n_wq = (size_t)EMB * EMB;
  const size_t n_wk = (size_t)KVDIM * EMB;

  bf16_t* xb  = (bf16_t*)d_ws;
  bf16_t* wqb = xb  + n_x;
  bf16_t* wkb = wqb + n_wq;
  bf16_t* wvb = wkb + n_wk;
  bf16_t* wob = wvb + n_wk;
  bf16_t* Qb  = wob + n_wq;                  // 4096*2048
  bf16_t* Kb  = Qb + (size_t)MROWS * EMB;    // 4096*512
  bf16_t* Vtb = Kb + (size_t)MROWS * KVDIM;  // (B*512)*2048 transposed V
  bf16_t* Yb  = Vtb + (size_t)MROWS * KVDIM; // 4096*2048

  dim3 blk(256);

  cvt_all<<<dim3(18432), blk, 0, stream>>>(
      (const float4*)x, (const float4*)wq, (const float4*)wk, (const float4*)wv, (const float4*)wo,
      (bf16x4*)xb, (bf16x4*)wqb, (bf16x4*)wkb, (bf16x4*)wvb, (bf16x4*)wob);

  const float qalpha = 0.08838834764831845f * 1.4426950408889634f;
  gemm_qkv<<<dim3(24, MROWS / 128), blk, 0, stream>>>(xb, wqb, wkb, wvb,
                                                      Qb, Kb, Vtb, qalpha);

  attn_fwd<<<dim3(16, NH, BATCH), blk, 0, stream>>>(Qb, Kb, Vtb, Yb);

  gemm_out<<<dim3(EMB / 128, MROWS / 128), blk, 0, stream>>>(Yb, wob, out, MROWS, EMB, EMB);
}